// Round 17
// baseline (220.707 us; speedup 1.0000x reference)
//
#include <hip/hip_runtime.h>
#include <hip/hip_bf16.h>

#define PB 8
#define PS 1024
#define PD 512
#define PH 8

typedef __attribute__((ext_vector_type(8))) short short8;
typedef __attribute__((ext_vector_type(4))) float f32x4;

__device__ inline ushort f2bf(float x) {
    union { float f; unsigned u; } c; c.f = x;
    unsigned u = c.u + 0x7fffu + ((c.u >> 16) & 1u);
    return (ushort)(u >> 16);
}
__device__ inline float bf2f(ushort u) {
    union { unsigned u; float f; } c; c.u = (unsigned)u << 16; return c.f;
}

__device__ inline void gload16(const void* g, void* l) {
    __builtin_amdgcn_global_load_lds(
        (const __attribute__((address_space(1))) void*)g,
        (__attribute__((address_space(3))) void*)l, 16, 0, 0);
}

// ---------------------------------------------------------------------------
// One dispatch for all 6 bf16 casts.
// ---------------------------------------------------------------------------
__global__ __launch_bounds__(256)
void cast_all(const float* __restrict__ q, const float* __restrict__ k,
              const float* __restrict__ v, const float* __restrict__ Wq,
              const float* __restrict__ Wv, const float* __restrict__ Wo,
              ushort* __restrict__ q_bf, ushort* __restrict__ k_bf,
              ushort* __restrict__ v_bf, ushort* __restrict__ Wq_bf,
              ushort* __restrict__ Wv_bf, ushort* __restrict__ Wo_bf)
{
    const int bid = blockIdx.x;
    const float* s; ushort* d; int base;
    if      (bid < 4096)  { s = q;  d = q_bf;  base = bid; }
    else if (bid < 8192)  { s = k;  d = k_bf;  base = bid - 4096; }
    else if (bid < 12288) { s = v;  d = v_bf;  base = bid - 8192; }
    else if (bid < 12544) { s = Wq; d = Wq_bf; base = bid - 12288; }
    else if (bid < 12800) { s = Wv; d = Wv_bf; base = bid - 12544; }
    else                  { s = Wo; d = Wo_bf; base = bid - 12800; }
    const int i = base * 256 + threadIdx.x;
    const float4 x = ((const float4*)s)[i];
    ushort4 o;
    o.x = f2bf(x.x); o.y = f2bf(x.y); o.z = f2bf(x.z); o.w = f2bf(x.w);
    ((ushort4*)d)[i] = o;
}

// ---------------------------------------------------------------------------
// All three projections in one dispatch (blockIdx.z = 0:q, 1:k, 2:v).
// z<2 -> bf16 head-split [(b*8+h)*1024+s][64]; z==2 -> plain V^T
// vhT[(b*8+h)*64+d][1024 s]. Epilogue: LDS C-bounce -> coalesced 16B stores.
// ---------------------------------------------------------------------------
__global__ __launch_bounds__(256)
void proj3(const ushort* __restrict__ q_bf, const ushort* __restrict__ k_bf,
           const ushort* __restrict__ v_bf, const ushort* __restrict__ Wq_bf,
           const ushort* __restrict__ Wv_bf, const float* __restrict__ bq,
           const float* __restrict__ bv, ushort* __restrict__ qh,
           ushort* __restrict__ kh, ushort* __restrict__ vhT)
{
    const int z = blockIdx.z;
    const ushort* A = (z == 0) ? q_bf : (z == 1) ? k_bf : v_bf;
    const ushort* B = (z == 2) ? Wv_bf : Wq_bf;
    const float* bias = (z == 2) ? bv : bq;

    __shared__ __align__(16) ushort S[128 * 136];   // 34.8 KB
    ushort* As = S;            // [0, 8192)
    ushort* Bs = S + 8192;     // [8192, 16384)
    const int tid = threadIdx.x;
    const int lane = tid & 63;
    const int wave = tid >> 6;
    const int wr = wave >> 1, wc = wave & 1;
    const int bm = blockIdx.x * 128, bn = blockIdx.y * 128;
    const int lrow = lane >> 3;
    const int lcol = (lane & 7) * 8;

    f32x4 acc[4][4] = {};

    for (int k0 = 0; k0 < 512; k0 += 64) {
#pragma unroll
        for (int i = 0; i < 4; ++i) {
            const int c = wave * 4 + i;
            gload16(A + (size_t)(bm + c * 8 + lrow) * 512 + k0 + lcol, &As[c * 512]);
            gload16(B + (size_t)(bn + c * 8 + lrow) * 512 + k0 + lcol, &Bs[c * 512]);
        }
        __syncthreads();
        short8 af[2][4], bf[2][4];
#pragma unroll
        for (int kk = 0; kk < 2; ++kk) {
#pragma unroll
            for (int m = 0; m < 4; ++m)
                af[kk][m] = *(const short8*)&As[(wr * 64 + m * 16 + (lane & 15)) * 64 + kk * 32 + (lane >> 4) * 8];
#pragma unroll
            for (int n = 0; n < 4; ++n)
                bf[kk][n] = *(const short8*)&Bs[(wc * 64 + n * 16 + (lane & 15)) * 64 + kk * 32 + (lane >> 4) * 8];
        }
#pragma unroll
        for (int kk = 0; kk < 2; ++kk)
#pragma unroll
            for (int m = 0; m < 4; ++m)
#pragma unroll
                for (int n = 0; n < 4; ++n)
                    acc[m][n] = __builtin_amdgcn_mfma_f32_16x16x32_bf16(af[kk][m], bf[kk][n], acc[m][n], 0, 0, 0);
        __syncthreads();
    }

    // ---- stage C into LDS (bf16, stride 136) ----
    if (z == 2) {
        // transposed: S[col*136 + row] so vhT streams contiguous in s
#pragma unroll
        for (int m = 0; m < 4; ++m)
#pragma unroll
            for (int n = 0; n < 4; ++n) {
                const int r0 = wr * 64 + m * 16 + (lane >> 4) * 4;
                const int cl = wc * 64 + n * 16 + (lane & 15);
                const float bi = bias[bn + cl];
                ushort4 o;
                o.x = f2bf(acc[m][n][0] + bi);
                o.y = f2bf(acc[m][n][1] + bi);
                o.z = f2bf(acc[m][n][2] + bi);
                o.w = f2bf(acc[m][n][3] + bi);
                *(ushort4*)&S[cl * 136 + r0] = o;
            }
    } else {
#pragma unroll
        for (int m = 0; m < 4; ++m)
#pragma unroll
            for (int n = 0; n < 4; ++n) {
                const int r0 = wr * 64 + m * 16 + (lane >> 4) * 4;
                const int cl = wc * 64 + n * 16 + (lane & 15);
                const float bi = bias[bn + cl];
#pragma unroll
                for (int r = 0; r < 4; ++r)
                    S[(r0 + r) * 136 + cl] = f2bf(acc[m][n][r] + bi);
            }
    }
    __syncthreads();

    // ---- coalesced 16B stores: 2048 chunks, 8 per thread ----
    const int b = bm >> 10, sbase = bm & 1023;
    if (z == 2) {
#pragma unroll
        for (int it = 0; it < 8; ++it) {
            const int c = it * 256 + tid;
            const int dloc = c >> 4, seg = c & 15;      // d-local, s-chunk
            const int h = (bn >> 6) + (dloc >> 6), d = dloc & 63;
            const uint4 v4 = *(const uint4*)&S[dloc * 136 + seg * 8];
            *(uint4*)&vhT[((size_t)((b * 8 + h) * 64 + d)) * 1024 + sbase + seg * 8] = v4;
        }
    } else {
        ushort* out = z ? kh : qh;
#pragma unroll
        for (int it = 0; it < 8; ++it) {
            const int c = it * 256 + tid;
            const int row = c >> 4, seg = c & 15;       // s-local, col-chunk
            const int h = (bn >> 6) + (seg >> 3), d8 = (seg & 7) * 8;
            const uint4 v4 = *(const uint4*)&S[row * 136 + seg * 8];
            *(uint4*)&out[(((size_t)(b * 8 + h)) * 1024 + sbase + row) * 64 + d8] = v4;
        }
    }
}

// ---------------------------------------------------------------------------
// QK^T per (b,h): raw bf16 logits (x0.125) into the first 2KB of each score
// row's 4KB slot, via LDS C-bounce -> coalesced 16B stores. Upper-triangular
// 128-blocks write f32 zeros. Flat grid, bh fastest-varying (XCD L2 share).
// ---------------------------------------------------------------------------
__global__ __launch_bounds__(256)
void qk_mfma(const ushort* __restrict__ qh, const ushort* __restrict__ kh,
             float* __restrict__ scores)
{
    const int d0 = blockIdx.x;           // 0..4095
    const int bh = d0 & 63;
    const int pair = d0 >> 6;            // 0..63
    const int kb = pair & 7, qb = pair >> 3;
    const int tid = threadIdx.x;
    if (kb > qb) {
        // masked region: write final zeros
        float* S = scores + ((size_t)bh << 20);
        const f32x4 z = {};
#pragma unroll
        for (int it = 0; it < 16; ++it) {
            const int f = it * 256 + tid;           // 4096 float4 total
            const int row = f >> 5, c4 = f & 31;
            __builtin_nontemporal_store(z,
                (f32x4*)&S[(size_t)(qb * 128 + row) * 1024 + kb * 128 + c4 * 4]);
        }
        return;
    }
    __shared__ __align__(16) ushort S[128 * 136];   // 34.8 KB
    ushort* As = S;
    ushort* Bs = S + 8192;
    const int lane = tid & 63, wave = tid >> 6;
    const int wr = wave >> 1, wc = wave & 1;
    const ushort* Ab = qh + ((size_t)bh * PS + qb * 128) * 64;
    const ushort* Bb = kh + ((size_t)bh * PS + kb * 128) * 64;

#pragma unroll
    for (int i = 0; i < 4; ++i) {
        const int c = wave * 4 + i;
        gload16(Ab + c * 512 + lane * 8, &As[c * 512]);
        gload16(Bb + c * 512 + lane * 8, &Bs[c * 512]);
    }
    __syncthreads();

    f32x4 acc[4][4] = {};
    short8 af[2][4], bf[2][4];
#pragma unroll
    for (int kk = 0; kk < 2; ++kk) {
#pragma unroll
        for (int m = 0; m < 4; ++m)
            af[kk][m] = *(const short8*)&As[(wr * 64 + m * 16 + (lane & 15)) * 64 + kk * 32 + (lane >> 4) * 8];
#pragma unroll
        for (int n = 0; n < 4; ++n)
            bf[kk][n] = *(const short8*)&Bs[(wc * 64 + n * 16 + (lane & 15)) * 64 + kk * 32 + (lane >> 4) * 8];
    }
#pragma unroll
    for (int kk = 0; kk < 2; ++kk)
#pragma unroll
        for (int m = 0; m < 4; ++m)
#pragma unroll
            for (int n = 0; n < 4; ++n)
                acc[m][n] = __builtin_amdgcn_mfma_f32_16x16x32_bf16(af[kk][m], bf[kk][n], acc[m][n], 0, 0, 0);

    __syncthreads();   // all fragment reads done before C overwrites S

    // ---- stage C bf16 (x0.125) into LDS, stride 136 ----
#pragma unroll
    for (int m = 0; m < 4; ++m)
#pragma unroll
        for (int n = 0; n < 4; ++n) {
            const int r0 = wr * 64 + m * 16 + (lane >> 4) * 4;
            const int cl = wc * 64 + n * 16 + (lane & 15);
#pragma unroll
            for (int r = 0; r < 4; ++r)
                S[(r0 + r) * 136 + cl] = f2bf(acc[m][n][r] * 0.125f);
        }
    __syncthreads();

    // ---- coalesced 16B stores of the raw tile ----
    ushort* Sr = (ushort*)(scores + ((size_t)bh << 20));
#pragma unroll
    for (int it = 0; it < 8; ++it) {
        const int c = it * 256 + tid;
        const int row = c >> 4, seg = c & 15;
        const uint4 v4 = *(const uint4*)&S[row * 136 + seg * 8];
        *(uint4*)&Sr[(size_t)(qb * 128 + row) * 2048 + kb * 128 + seg * 8] = v4;
    }
}

// ---------------------------------------------------------------------------
// Fused row softmax + PV, v3b: 512 threads = 8 waves = 8 rows per block.
// SINGLE-VARIABLE test vs r16: cum[16] restored (kills the serial
// exp-recompute chain in the decay pass), launch bounds relaxed to (512)
// so the extra ~16 live VGPRs don't spill. No PV unroll.
// ---------------------------------------------------------------------------
__global__ __launch_bounds__(512)
void rowpv3(float* __restrict__ scores, const ushort* __restrict__ vhT,
            const float* __restrict__ gammas, ushort* __restrict__ attn)
{
    const int d0 = blockIdx.x;           // 0..8191
    const int bh = d0 & 63, h = bh & 7;
    const int b = bh >> 3;
    const int rb = d0 >> 6;              // 8-row block 0..127
    const int w = threadIdx.x >> 6;      // wave = row within block, 0..7
    const int lane = threadIdx.x & 63;
    const int i = rb * 8 + w;
    const int nt = (rb >> 3) + 1;        // 64-col k-tiles for this block
    const int G = (nt + 3) >> 2;         // 1..4 col-groups of 4 per lane
    const int base = lane * 4 * G;       // covers [0, 256G) >= nt*64
    const int lim = ((i >> 7) + 1) * 128;

    __shared__ __align__(16) ushort P[8 * 1024];    // 16 KB, swizzled
    __shared__ float RED[2][8][68];                 // 4.3 KB padded

    float* srow = scores + ((size_t)bh << 20) + ((size_t)i << 10);
    const ushort* rraw = (const ushort*)srow;

    union U4 { uint2 v; ushort u[4]; };
    float l[16];
#pragma unroll
    for (int g = 0; g < 4; ++g) {
        if (g < G) {
            U4 a; a.v = *(const uint2*)(rraw + base + g * 4);
#pragma unroll
            for (int j = 0; j < 4; ++j)
                l[g * 4 + j] = (base + g * 4 + j <= i) ? bf2f(a.u[j]) : -3.0e38f;
        }
    }

    // softmax-1 max
    float m1 = -3.0e38f;
#pragma unroll
    for (int g = 0; g < 4; ++g) if (g < G)
#pragma unroll
        for (int j = 0; j < 4; ++j) m1 = fmaxf(m1, l[g * 4 + j]);
#pragma unroll
    for (int off = 32; off; off >>= 1) m1 = fmaxf(m1, __shfl_xor(m1, off));

    // exp + in-lane inclusive cumsum (kept in cum[] — no serial recompute)
    float cum[16];
    float lsum = 0.f;
#pragma unroll
    for (int g = 0; g < 4; ++g) if (g < G)
#pragma unroll
        for (int j = 0; j < 4; ++j) {
            const int c = g * 4 + j;
            const float e = (base + c <= i) ? __expf(l[c] - m1) : 0.f;
            lsum += e;
            cum[c] = lsum;
        }
    // single 64-lane scan of lane totals
    float incl = lsum;
#pragma unroll
    for (int off = 1; off < 64; off <<= 1) {
        const float y = __shfl_up(incl, off);
        if (lane >= off) incl += y;
    }
    const float excl = incl - lsum;
    const float es = __shfl(incl, 63);
    const float inv_es = __builtin_amdgcn_rcpf(es);
    const float gamma = -fabsf(gammas[h]);
    const float M2 = fmaxf(m1, 0.f);     // shift for softmax-2 (exact)

    // decay + softmax-2 numerator (per-column independent now)
    float s2 = 0.f;
#pragma unroll
    for (int g = 0; g < 4; ++g) if (g < G)
#pragma unroll
        for (int j = 0; j < 4; ++j) {
            const int c = g * 4 + j;
            if (base + c <= i) {
                const float sfxn = fmaxf((es - (excl + cum[c])) * inv_es, 0.f);
                const float pe = (float)(i - (base + c));
                const float dist = __builtin_amdgcn_sqrtf(sfxn * pe);
                const float eff = fmaxf(__expf(gamma * dist), 1e-5f);
                const float p = __expf(l[c] * eff - M2);
                l[c] = p; s2 += p;
            } else {
                l[c] = 0.f;
            }
        }
#pragma unroll
    for (int off = 32; off; off >>= 1) s2 += __shfl_xor(s2, off);
    const float inv2 = __builtin_amdgcn_rcpf(s2);
#pragma unroll
    for (int g = 0; g < 4; ++g) if (g < G)
#pragma unroll
        for (int j = 0; j < 4; ++j) l[g * 4 + j] *= inv2;

    // ---- P -> LDS bf16; logical 16B chunk lc -> physical (lc&~7)|((lc^w)&7)
#pragma unroll
    for (int g = 0; g < 4; ++g) {
        if (g < G) {
            U4 p;
#pragma unroll
            for (int j = 0; j < 4; ++j) p.u[j] = f2bf(l[g * 4 + j]);
            const int col = base + g * 4;
            const int lc = col >> 3;
            const int sp = (lc & ~7) | ((lc ^ w) & 7);
            *(uint2*)&P[w * 1024 + sp * 8 + (col & 7)] = p.v;
        }
    }
    __syncthreads();

    // ---- final f32 score stores: REGULAR stores (L2 write-combining)
#pragma unroll
    for (int g = 0; g < 4; ++g) {
        if (g < G && base + g * 4 < lim) {
            f32x4 v;
            v[0] = l[g * 4 + 0]; v[1] = l[g * 4 + 1];
            v[2] = l[g * 4 + 2]; v[3] = l[g * 4 + 3];
            *(f32x4*)&srow[base + g * 4] = v;
        }
    }

    // ---- PV MFMA: waves (kq in 0..1, nn in 0..3); A rows 8-15 duplicated,
    // their C rows discarded. V^T direct from global (L2).
    const int kq = w >> 2, nn = w & 3;
    const int row16 = lane & 15, kg = lane >> 4;
    const int arow = lane & 7;           // P row supplied to the A-fragment
    const ushort* vb = vhT + ((size_t)bh << 16) + (size_t)(nn * 16 + row16) * 1024;
    f32x4 acc = {};
    for (int t = kq; t < nt; t += 2) {
#pragma unroll
        for (int kk = 0; kk < 2; ++kk) {
            const int chunk = t * 8 + ((kk * 4 + kg) ^ arow);
            const short8 af = *(const short8*)&P[arow * 1024 + chunk * 8];
            const short8 bf = *(const short8*)&vb[t * 64 + kk * 32 + kg * 8];
            acc = __builtin_amdgcn_mfma_f32_16x16x32_bf16(af, bf, acc, 0, 0, 0);
        }
    }

    // ---- reduce 2 kq partials (C rows 0..7 only), write attn
    if (kg < 2) {
#pragma unroll
        for (int r = 0; r < 4; ++r)
            RED[kq][kg * 4 + r][nn * 16 + row16] = acc[r];
    }
    __syncthreads();
    const float o = RED[0][w][lane] + RED[1][w][lane];
    attn[((size_t)(b * 1024 + i)) * 512 + h * 64 + lane] = f2bf(o);
}

// ---------------------------------------------------------------------------
// Output GEMM: f32 out = attn(bf16) @ Wo^T + bo
// ---------------------------------------------------------------------------
__global__ __launch_bounds__(256)
void gemm_out(const ushort* __restrict__ A, const ushort* __restrict__ B,
              const float* __restrict__ bias, float* __restrict__ out)
{
    __shared__ __align__(16) ushort As[128 * 64];
    __shared__ __align__(16) ushort Bs[128 * 64];
    const int tid = threadIdx.x;
    const int lane = tid & 63;
    const int wave = tid >> 6;
    const int wr = wave >> 1, wc = wave & 1;
    const int bm = blockIdx.x * 128, bn = blockIdx.y * 128;
    const int lrow = lane >> 3;
    const int lcol = (lane & 7) * 8;

    f32x4 acc[4][4] = {};

    for (int k0 = 0; k0 < 512; k0 += 64) {
#pragma unroll
        for (int i = 0; i < 4; ++i) {
            const int c = wave * 4 + i;
            gload16(A + (size_t)(bm + c * 8 + lrow) * 512 + k0 + lcol, &As[c * 512]);
            gload16(B + (size_t)(bn + c * 8 + lrow) * 512 + k0 + lcol, &Bs[c * 512]);
        }
        __syncthreads();
        short8 af[2][4], bf[2][4];
#pragma unroll
        for (int kk = 0; kk < 2; ++kk) {
#pragma unroll
            for (int m = 0; m < 4; ++m)
                af[kk][m] = *(const short8*)&As[(wr * 64 + m * 16 + (lane & 15)) * 64 + kk * 32 + (lane >> 4) * 8];
#pragma unroll
            for (int n = 0; n < 4; ++n)
                bf[kk][n] = *(const short8*)&Bs[(wc * 64 + n * 16 + (lane & 15)) * 64 + kk * 32 + (lane >> 4) * 8];
        }
#pragma unroll
        for (int kk = 0; kk < 2; ++kk)
#pragma unroll
            for (int m = 0; m < 4; ++m)
#pragma unroll
                for (int n = 0; n < 4; ++n)
                    acc[m][n] = __builtin_amdgcn_mfma_f32_16x16x32_bf16(af[kk][m], bf[kk][n], acc[m][n], 0, 0, 0);
        __syncthreads();
    }

#pragma unroll
    for (int m = 0; m < 4; ++m)
#pragma unroll
        for (int n = 0; n < 4; ++n)
#pragma unroll
            for (int r = 0; r < 4; ++r) {
                const int row = bm + wr * 64 + m * 16 + (lane >> 4) * 4 + r;
                const int col = bn + wc * 64 + n * 16 + (lane & 15);
                out[(size_t)row * 512 + col] = acc[m][n][r] + bias[col];
            }
}

// ---------------------------------------------------------------------------
extern "C" void kernel_launch(void* const* d_in, const int* in_sizes, int n_in,
                              void* d_out, int out_size, void* d_ws, size_t ws_size,
                              hipStream_t stream)
{
    const float* q      = (const float*)d_in[0];
    const float* k      = (const float*)d_in[1];
    const float* v      = (const float*)d_in[2];
    const float* Wq     = (const float*)d_in[4];
    const float* bq     = (const float*)d_in[5];
    const float* Wv     = (const float*)d_in[6];
    const float* bv     = (const float*)d_in[7];
    const float* Wo     = (const float*)d_in[8];
    const float* bo     = (const float*)d_in[9];
    const float* gammas = (const float*)d_in[10];

    float* out    = (float*)d_out;                       // [8,1024,512] f32
    float* scores = out + (size_t)PB * PS * PD;          // [64,1024,1024] f32

    char* w = (char*)d_ws;
    ushort* q_bf  = (ushort*)(w);                        // 8 MB
    ushort* k_bf  = (ushort*)(w + (8u  << 20));          // 8 MB
    ushort* v_bf  = (ushort*)(w + (16u << 20));          // 8 MB
    ushort* Wq_bf = (ushort*)(w + (24u << 20));          // 0.5 MB
    ushort* Wv_bf = (ushort*)(w + (24u << 20) + (1u << 19));
    ushort* Wo_bf = (ushort*)(w + (25u << 20));
    ushort* qh    = (ushort*)(w + (26u << 20));          // 8 MB
    ushort* kh    = (ushort*)(w + (34u << 20));          // 8 MB
    ushort* vhT   = (ushort*)(w + (42u << 20));          // 8 MB (plain transpose)
    ushort* attn  = (ushort*)(w + (50u << 20));          // 8 MB

    cast_all<<<13056, 256, 0, stream>>>(q, k, v, Wq, Wv, Wo,
                                        q_bf, k_bf, v_bf, Wq_bf, Wv_bf, Wo_bf);

    proj3<<<dim3(64, 4, 3), 256, 0, stream>>>(q_bf, k_bf, v_bf, Wq_bf, Wv_bf,
                                              bq, bv, qh, kh, vhT);

    qk_mfma<<<4096, 256, 0, stream>>>(qh, kh, scores);
    rowpv3<<<8192, 512, 0, stream>>>(scores, vhT, gammas, attn);

    gemm_out<<<dim3(64, 4), 256, 0, stream>>>(attn, Wo_bf, bo, out);
}

// Round 18
// 204.725 us; speedup vs baseline: 1.0781x; 1.0781x over previous
//
#include <hip/hip_runtime.h>
#include <hip/hip_bf16.h>

#define PB 8
#define PS 1024
#define PD 512
#define PH 8

typedef __attribute__((ext_vector_type(8))) short short8;
typedef __attribute__((ext_vector_type(4))) float f32x4;

__device__ inline ushort f2bf(float x) {
    union { float f; unsigned u; } c; c.f = x;
    unsigned u = c.u + 0x7fffu + ((c.u >> 16) & 1u);
    return (ushort)(u >> 16);
}
__device__ inline float bf2f(ushort u) {
    union { unsigned u; float f; } c; c.u = (unsigned)u << 16; return c.f;
}

__device__ inline void gload16(const void* g, void* l) {
    __builtin_amdgcn_global_load_lds(
        (const __attribute__((address_space(1))) void*)g,
        (__attribute__((address_space(3))) void*)l, 16, 0, 0);
}

// ---------------------------------------------------------------------------
// One dispatch for all 6 bf16 casts.
// ---------------------------------------------------------------------------
__global__ __launch_bounds__(256)
void cast_all(const float* __restrict__ q, const float* __restrict__ k,
              const float* __restrict__ v, const float* __restrict__ Wq,
              const float* __restrict__ Wv, const float* __restrict__ Wo,
              ushort* __restrict__ q_bf, ushort* __restrict__ k_bf,
              ushort* __restrict__ v_bf, ushort* __restrict__ Wq_bf,
              ushort* __restrict__ Wv_bf, ushort* __restrict__ Wo_bf)
{
    const int bid = blockIdx.x;
    const float* s; ushort* d; int base;
    if      (bid < 4096)  { s = q;  d = q_bf;  base = bid; }
    else if (bid < 8192)  { s = k;  d = k_bf;  base = bid - 4096; }
    else if (bid < 12288) { s = v;  d = v_bf;  base = bid - 8192; }
    else if (bid < 12544) { s = Wq; d = Wq_bf; base = bid - 12288; }
    else if (bid < 12800) { s = Wv; d = Wv_bf; base = bid - 12544; }
    else                  { s = Wo; d = Wo_bf; base = bid - 12800; }
    const int i = base * 256 + threadIdx.x;
    const float4 x = ((const float4*)s)[i];
    ushort4 o;
    o.x = f2bf(x.x); o.y = f2bf(x.y); o.z = f2bf(x.z); o.w = f2bf(x.w);
    ((ushort4*)d)[i] = o;
}

// ---------------------------------------------------------------------------
// All three projections in one dispatch (blockIdx.z = 0:q, 1:k, 2:v).
// z<2 -> bf16 head-split [(b*8+h)*1024+s][64]; z==2 -> plain V^T
// vhT[(b*8+h)*64+d][1024 s]. Epilogue: LDS C-bounce -> coalesced 16B stores.
// ---------------------------------------------------------------------------
__global__ __launch_bounds__(256)
void proj3(const ushort* __restrict__ q_bf, const ushort* __restrict__ k_bf,
           const ushort* __restrict__ v_bf, const ushort* __restrict__ Wq_bf,
           const ushort* __restrict__ Wv_bf, const float* __restrict__ bq,
           const float* __restrict__ bv, ushort* __restrict__ qh,
           ushort* __restrict__ kh, ushort* __restrict__ vhT)
{
    const int z = blockIdx.z;
    const ushort* A = (z == 0) ? q_bf : (z == 1) ? k_bf : v_bf;
    const ushort* B = (z == 2) ? Wv_bf : Wq_bf;
    const float* bias = (z == 2) ? bv : bq;

    __shared__ __align__(16) ushort S[128 * 136];   // 34.8 KB
    ushort* As = S;            // [0, 8192)
    ushort* Bs = S + 8192;     // [8192, 16384)
    const int tid = threadIdx.x;
    const int lane = tid & 63;
    const int wave = tid >> 6;
    const int wr = wave >> 1, wc = wave & 1;
    const int bm = blockIdx.x * 128, bn = blockIdx.y * 128;
    const int lrow = lane >> 3;
    const int lcol = (lane & 7) * 8;

    f32x4 acc[4][4] = {};

    for (int k0 = 0; k0 < 512; k0 += 64) {
#pragma unroll
        for (int i = 0; i < 4; ++i) {
            const int c = wave * 4 + i;
            gload16(A + (size_t)(bm + c * 8 + lrow) * 512 + k0 + lcol, &As[c * 512]);
            gload16(B + (size_t)(bn + c * 8 + lrow) * 512 + k0 + lcol, &Bs[c * 512]);
        }
        __syncthreads();
        short8 af[2][4], bf[2][4];
#pragma unroll
        for (int kk = 0; kk < 2; ++kk) {
#pragma unroll
            for (int m = 0; m < 4; ++m)
                af[kk][m] = *(const short8*)&As[(wr * 64 + m * 16 + (lane & 15)) * 64 + kk * 32 + (lane >> 4) * 8];
#pragma unroll
            for (int n = 0; n < 4; ++n)
                bf[kk][n] = *(const short8*)&Bs[(wc * 64 + n * 16 + (lane & 15)) * 64 + kk * 32 + (lane >> 4) * 8];
        }
#pragma unroll
        for (int kk = 0; kk < 2; ++kk)
#pragma unroll
            for (int m = 0; m < 4; ++m)
#pragma unroll
                for (int n = 0; n < 4; ++n)
                    acc[m][n] = __builtin_amdgcn_mfma_f32_16x16x32_bf16(af[kk][m], bf[kk][n], acc[m][n], 0, 0, 0);
        __syncthreads();
    }

    // ---- stage C into LDS (bf16, stride 136) ----
    if (z == 2) {
        // transposed: S[col*136 + row] so vhT streams contiguous in s
#pragma unroll
        for (int m = 0; m < 4; ++m)
#pragma unroll
            for (int n = 0; n < 4; ++n) {
                const int r0 = wr * 64 + m * 16 + (lane >> 4) * 4;
                const int cl = wc * 64 + n * 16 + (lane & 15);
                const float bi = bias[bn + cl];
                ushort4 o;
                o.x = f2bf(acc[m][n][0] + bi);
                o.y = f2bf(acc[m][n][1] + bi);
                o.z = f2bf(acc[m][n][2] + bi);
                o.w = f2bf(acc[m][n][3] + bi);
                *(ushort4*)&S[cl * 136 + r0] = o;
            }
    } else {
#pragma unroll
        for (int m = 0; m < 4; ++m)
#pragma unroll
            for (int n = 0; n < 4; ++n) {
                const int r0 = wr * 64 + m * 16 + (lane >> 4) * 4;
                const int cl = wc * 64 + n * 16 + (lane & 15);
                const float bi = bias[bn + cl];
#pragma unroll
                for (int r = 0; r < 4; ++r)
                    S[(r0 + r) * 136 + cl] = f2bf(acc[m][n][r] + bi);
            }
    }
    __syncthreads();

    // ---- coalesced 16B stores: 2048 chunks, 8 per thread ----
    const int b = bm >> 10, sbase = bm & 1023;
    if (z == 2) {
#pragma unroll
        for (int it = 0; it < 8; ++it) {
            const int c = it * 256 + tid;
            const int dloc = c >> 4, seg = c & 15;      // d-local, s-chunk
            const int h = (bn >> 6) + (dloc >> 6), d = dloc & 63;
            const uint4 v4 = *(const uint4*)&S[dloc * 136 + seg * 8];
            *(uint4*)&vhT[((size_t)((b * 8 + h) * 64 + d)) * 1024 + sbase + seg * 8] = v4;
        }
    } else {
        ushort* out = z ? kh : qh;
#pragma unroll
        for (int it = 0; it < 8; ++it) {
            const int c = it * 256 + tid;
            const int row = c >> 4, seg = c & 15;       // s-local, col-chunk
            const int h = (bn >> 6) + (seg >> 3), d8 = (seg & 7) * 8;
            const uint4 v4 = *(const uint4*)&S[row * 136 + seg * 8];
            *(uint4*)&out[(((size_t)(b * 8 + h)) * 1024 + sbase + row) * 64 + d8] = v4;
        }
    }
}

// ---------------------------------------------------------------------------
// QK^T per (b,h): raw bf16 logits (x0.125) into the first 2KB of each score
// row's 4KB slot, via LDS C-bounce -> coalesced 16B stores. Upper-triangular
// 128-blocks write f32 zeros. Flat grid, bh fastest-varying (XCD L2 share).
// ---------------------------------------------------------------------------
__global__ __launch_bounds__(256)
void qk_mfma(const ushort* __restrict__ qh, const ushort* __restrict__ kh,
             float* __restrict__ scores)
{
    const int d0 = blockIdx.x;           // 0..4095
    const int bh = d0 & 63;
    const int pair = d0 >> 6;            // 0..63
    const int kb = pair & 7, qb = pair >> 3;
    const int tid = threadIdx.x;
    if (kb > qb) {
        // masked region: write final zeros
        float* S = scores + ((size_t)bh << 20);
        const f32x4 z = {};
#pragma unroll
        for (int it = 0; it < 16; ++it) {
            const int f = it * 256 + tid;           // 4096 float4 total
            const int row = f >> 5, c4 = f & 31;
            __builtin_nontemporal_store(z,
                (f32x4*)&S[(size_t)(qb * 128 + row) * 1024 + kb * 128 + c4 * 4]);
        }
        return;
    }
    __shared__ __align__(16) ushort S[128 * 136];   // 34.8 KB
    ushort* As = S;
    ushort* Bs = S + 8192;
    const int lane = tid & 63, wave = tid >> 6;
    const int wr = wave >> 1, wc = wave & 1;
    const ushort* Ab = qh + ((size_t)bh * PS + qb * 128) * 64;
    const ushort* Bb = kh + ((size_t)bh * PS + kb * 128) * 64;

#pragma unroll
    for (int i = 0; i < 4; ++i) {
        const int c = wave * 4 + i;
        gload16(Ab + c * 512 + lane * 8, &As[c * 512]);
        gload16(Bb + c * 512 + lane * 8, &Bs[c * 512]);
    }
    __syncthreads();

    f32x4 acc[4][4] = {};
    short8 af[2][4], bf[2][4];
#pragma unroll
    for (int kk = 0; kk < 2; ++kk) {
#pragma unroll
        for (int m = 0; m < 4; ++m)
            af[kk][m] = *(const short8*)&As[(wr * 64 + m * 16 + (lane & 15)) * 64 + kk * 32 + (lane >> 4) * 8];
#pragma unroll
        for (int n = 0; n < 4; ++n)
            bf[kk][n] = *(const short8*)&Bs[(wc * 64 + n * 16 + (lane & 15)) * 64 + kk * 32 + (lane >> 4) * 8];
    }
#pragma unroll
    for (int kk = 0; kk < 2; ++kk)
#pragma unroll
        for (int m = 0; m < 4; ++m)
#pragma unroll
            for (int n = 0; n < 4; ++n)
                acc[m][n] = __builtin_amdgcn_mfma_f32_16x16x32_bf16(af[kk][m], bf[kk][n], acc[m][n], 0, 0, 0);

    __syncthreads();   // all fragment reads done before C overwrites S

    // ---- stage C bf16 (x0.125) into LDS, stride 136 ----
#pragma unroll
    for (int m = 0; m < 4; ++m)
#pragma unroll
        for (int n = 0; n < 4; ++n) {
            const int r0 = wr * 64 + m * 16 + (lane >> 4) * 4;
            const int cl = wc * 64 + n * 16 + (lane & 15);
#pragma unroll
            for (int r = 0; r < 4; ++r)
                S[(r0 + r) * 136 + cl] = f2bf(acc[m][n][r] * 0.125f);
        }
    __syncthreads();

    // ---- coalesced 16B stores of the raw tile ----
    ushort* Sr = (ushort*)(scores + ((size_t)bh << 20));
#pragma unroll
    for (int it = 0; it < 8; ++it) {
        const int c = it * 256 + tid;
        const int row = c >> 4, seg = c & 15;
        const uint4 v4 = *(const uint4*)&S[row * 136 + seg * 8];
        *(uint4*)&Sr[(size_t)(qb * 128 + row) * 2048 + kb * 128 + seg * 8] = v4;
    }
}

// ---------------------------------------------------------------------------
// Fused row softmax + PV, v3: 512 threads = 8 waves = 8 rows per block.
// Final score stores are REGULAR (cached) stores: L2 merges the 16B chunks
// into full lines (round-12 NT stores showed 2.6x write amplification).
// Register-lean row phase (no cum[], serial recompute) — r15/r17 showed
// fatter variants lose more to occupancy/spills than the chain costs.
// ---------------------------------------------------------------------------
__global__ __launch_bounds__(512, 8)
void rowpv3(float* __restrict__ scores, const ushort* __restrict__ vhT,
            const float* __restrict__ gammas, ushort* __restrict__ attn)
{
    const int d0 = blockIdx.x;           // 0..8191
    const int bh = d0 & 63, h = bh & 7;
    const int b = bh >> 3;
    const int rb = d0 >> 6;              // 8-row block 0..127
    const int w = threadIdx.x >> 6;      // wave = row within block, 0..7
    const int lane = threadIdx.x & 63;
    const int i = rb * 8 + w;
    const int nt = (rb >> 3) + 1;        // 64-col k-tiles for this block
    const int G = (nt + 3) >> 2;         // 1..4 col-groups of 4 per lane
    const int base = lane * 4 * G;       // covers [0, 256G) >= nt*64
    const int lim = ((i >> 7) + 1) * 128;

    __shared__ __align__(16) ushort P[8 * 1024];    // 16 KB, swizzled
    __shared__ float RED[2][8][68];                 // 4.3 KB padded

    float* srow = scores + ((size_t)bh << 20) + ((size_t)i << 10);
    const ushort* rraw = (const ushort*)srow;

    union U4 { uint2 v; ushort u[4]; };
    float l[16];
#pragma unroll
    for (int g = 0; g < 4; ++g) {
        if (g < G) {
            U4 a; a.v = *(const uint2*)(rraw + base + g * 4);
#pragma unroll
            for (int j = 0; j < 4; ++j)
                l[g * 4 + j] = (base + g * 4 + j <= i) ? bf2f(a.u[j]) : -3.0e38f;
        }
    }

    // softmax-1 max
    float m1 = -3.0e38f;
#pragma unroll
    for (int g = 0; g < 4; ++g) if (g < G)
#pragma unroll
        for (int j = 0; j < 4; ++j) m1 = fmaxf(m1, l[g * 4 + j]);
#pragma unroll
    for (int off = 32; off; off >>= 1) m1 = fmaxf(m1, __shfl_xor(m1, off));

    // lane sum of exp (masked cols underflow to 0)
    float lsum = 0.f;
#pragma unroll
    for (int g = 0; g < 4; ++g) if (g < G)
#pragma unroll
        for (int j = 0; j < 4; ++j) lsum += __expf(l[g * 4 + j] - m1);
    // single 64-lane scan of lane totals
    float incl = lsum;
#pragma unroll
    for (int off = 1; off < 64; off <<= 1) {
        const float y = __shfl_up(incl, off);
        if (lane >= off) incl += y;
    }
    const float excl = incl - lsum;
    const float es = __shfl(incl, 63);
    const float inv_es = __builtin_amdgcn_rcpf(es);
    const float gamma = -fabsf(gammas[h]);
    const float M2 = fmaxf(m1, 0.f);     // shift for softmax-2 (exact)

    // decay + softmax-2 numerator (running cumsum recompute)
    float racc = excl;
    float s2 = 0.f;
#pragma unroll
    for (int g = 0; g < 4; ++g) if (g < G)
#pragma unroll
        for (int j = 0; j < 4; ++j) {
            const int c = g * 4 + j;
            if (base + c <= i) {
                racc += __expf(l[c] - m1);
                const float sfxn = fmaxf((es - racc) * inv_es, 0.f);
                const float pe = (float)(i - (base + c));
                const float dist = __builtin_amdgcn_sqrtf(sfxn * pe);
                const float eff = fmaxf(__expf(gamma * dist), 1e-5f);
                const float p = __expf(l[c] * eff - M2);
                l[c] = p; s2 += p;
            } else {
                l[c] = 0.f;
            }
        }
#pragma unroll
    for (int off = 32; off; off >>= 1) s2 += __shfl_xor(s2, off);
    const float inv2 = __builtin_amdgcn_rcpf(s2);
#pragma unroll
    for (int g = 0; g < 4; ++g) if (g < G)
#pragma unroll
        for (int j = 0; j < 4; ++j) l[g * 4 + j] *= inv2;

    // ---- P -> LDS bf16; logical 16B chunk lc -> physical (lc&~7)|((lc^w)&7)
#pragma unroll
    for (int g = 0; g < 4; ++g) {
        if (g < G) {
            U4 p;
#pragma unroll
            for (int j = 0; j < 4; ++j) p.u[j] = f2bf(l[g * 4 + j]);
            const int col = base + g * 4;
            const int lc = col >> 3;
            const int sp = (lc & ~7) | ((lc ^ w) & 7);
            *(uint2*)&P[w * 1024 + sp * 8 + (col & 7)] = p.v;
        }
    }
    __syncthreads();

    // ---- final f32 score stores: REGULAR stores (L2 write-combining)
#pragma unroll
    for (int g = 0; g < 4; ++g) {
        if (g < G && base + g * 4 < lim) {
            f32x4 v;
            v[0] = l[g * 4 + 0]; v[1] = l[g * 4 + 1];
            v[2] = l[g * 4 + 2]; v[3] = l[g * 4 + 3];
            *(f32x4*)&srow[base + g * 4] = v;
        }
    }

    // ---- PV MFMA: waves (kq in 0..1, nn in 0..3); A rows 8-15 duplicated,
    // their C rows discarded. V^T direct from global (L2).
    const int kq = w >> 2, nn = w & 3;
    const int row16 = lane & 15, kg = lane >> 4;
    const int arow = lane & 7;           // P row supplied to the A-fragment
    const ushort* vb = vhT + ((size_t)bh << 16) + (size_t)(nn * 16 + row16) * 1024;
    f32x4 acc = {};
    for (int t = kq; t < nt; t += 2) {
#pragma unroll
        for (int kk = 0; kk < 2; ++kk) {
            const int chunk = t * 8 + ((kk * 4 + kg) ^ arow);
            const short8 af = *(const short8*)&P[arow * 1024 + chunk * 8];
            const short8 bf = *(const short8*)&vb[t * 64 + kk * 32 + kg * 8];
            acc = __builtin_amdgcn_mfma_f32_16x16x32_bf16(af, bf, acc, 0, 0, 0);
        }
    }

    // ---- reduce 2 kq partials (C rows 0..7 only), write attn
    if (kg < 2) {
#pragma unroll
        for (int r = 0; r < 4; ++r)
            RED[kq][kg * 4 + r][nn * 16 + row16] = acc[r];
    }
    __syncthreads();
    const float o = RED[0][w][lane] + RED[1][w][lane];
    attn[((size_t)(b * 1024 + i)) * 512 + h * 64 + lane] = f2bf(o);
}

// ---------------------------------------------------------------------------
// Output GEMM: f32 out = attn(bf16) @ Wo^T + bo
// ---------------------------------------------------------------------------
__global__ __launch_bounds__(256)
void gemm_out(const ushort* __restrict__ A, const ushort* __restrict__ B,
              const float* __restrict__ bias, float* __restrict__ out)
{
    __shared__ __align__(16) ushort As[128 * 64];
    __shared__ __align__(16) ushort Bs[128 * 64];
    const int tid = threadIdx.x;
    const int lane = tid & 63;
    const int wave = tid >> 6;
    const int wr = wave >> 1, wc = wave & 1;
    const int bm = blockIdx.x * 128, bn = blockIdx.y * 128;
    const int lrow = lane >> 3;
    const int lcol = (lane & 7) * 8;

    f32x4 acc[4][4] = {};

    for (int k0 = 0; k0 < 512; k0 += 64) {
#pragma unroll
        for (int i = 0; i < 4; ++i) {
            const int c = wave * 4 + i;
            gload16(A + (size_t)(bm + c * 8 + lrow) * 512 + k0 + lcol, &As[c * 512]);
            gload16(B + (size_t)(bn + c * 8 + lrow) * 512 + k0 + lcol, &Bs[c * 512]);
        }
        __syncthreads();
        short8 af[2][4], bf[2][4];
#pragma unroll
        for (int kk = 0; kk < 2; ++kk) {
#pragma unroll
            for (int m = 0; m < 4; ++m)
                af[kk][m] = *(const short8*)&As[(wr * 64 + m * 16 + (lane & 15)) * 64 + kk * 32 + (lane >> 4) * 8];
#pragma unroll
            for (int n = 0; n < 4; ++n)
                bf[kk][n] = *(const short8*)&Bs[(wc * 64 + n * 16 + (lane & 15)) * 64 + kk * 32 + (lane >> 4) * 8];
        }
#pragma unroll
        for (int kk = 0; kk < 2; ++kk)
#pragma unroll
            for (int m = 0; m < 4; ++m)
#pragma unroll
                for (int n = 0; n < 4; ++n)
                    acc[m][n] = __builtin_amdgcn_mfma_f32_16x16x32_bf16(af[kk][m], bf[kk][n], acc[m][n], 0, 0, 0);
        __syncthreads();
    }

#pragma unroll
    for (int m = 0; m < 4; ++m)
#pragma unroll
        for (int n = 0; n < 4; ++n)
#pragma unroll
            for (int r = 0; r < 4; ++r) {
                const int row = bm + wr * 64 + m * 16 + (lane >> 4) * 4 + r;
                const int col = bn + wc * 64 + n * 16 + (lane & 15);
                out[(size_t)row * 512 + col] = acc[m][n][r] + bias[col];
            }
}

// ---------------------------------------------------------------------------
extern "C" void kernel_launch(void* const* d_in, const int* in_sizes, int n_in,
                              void* d_out, int out_size, void* d_ws, size_t ws_size,
                              hipStream_t stream)
{
    const float* q      = (const float*)d_in[0];
    const float* k      = (const float*)d_in[1];
    const float* v      = (const float*)d_in[2];
    const float* Wq     = (const float*)d_in[4];
    const float* bq     = (const float*)d_in[5];
    const float* Wv     = (const float*)d_in[6];
    const float* bv     = (const float*)d_in[7];
    const float* Wo     = (const float*)d_in[8];
    const float* bo     = (const float*)d_in[9];
    const float* gammas = (const float*)d_in[10];

    float* out    = (float*)d_out;                       // [8,1024,512] f32
    float* scores = out + (size_t)PB * PS * PD;          // [64,1024,1024] f32

    char* w = (char*)d_ws;
    ushort* q_bf  = (ushort*)(w);                        // 8 MB
    ushort* k_bf  = (ushort*)(w + (8u  << 20));          // 8 MB
    ushort* v_bf  = (ushort*)(w + (16u << 20));          // 8 MB
    ushort* Wq_bf = (ushort*)(w + (24u << 20));          // 0.5 MB
    ushort* Wv_bf = (ushort*)(w + (24u << 20) + (1u << 19));
    ushort* Wo_bf = (ushort*)(w + (25u << 20));
    ushort* qh    = (ushort*)(w + (26u << 20));          // 8 MB
    ushort* kh    = (ushort*)(w + (34u << 20));          // 8 MB
    ushort* vhT   = (ushort*)(w + (42u << 20));          // 8 MB (plain transpose)
    ushort* attn  = (ushort*)(w + (50u << 20));          // 8 MB

    cast_all<<<13056, 256, 0, stream>>>(q, k, v, Wq, Wv, Wo,
                                        q_bf, k_bf, v_bf, Wq_bf, Wv_bf, Wo_bf);

    proj3<<<dim3(64, 4, 3), 256, 0, stream>>>(q_bf, k_bf, v_bf, Wq_bf, Wv_bf,
                                              bq, bv, qh, kh, vhT);

    qk_mfma<<<4096, 256, 0, stream>>>(qh, kh, scores);
    rowpv3<<<8192, 512, 0, stream>>>(scores, vhT, gammas, attn);

    gemm_out<<<dim3(64, 4), 256, 0, stream>>>(attn, Wo_bf, bo, out);
}

// Round 19
// 202.985 us; speedup vs baseline: 1.0873x; 1.0086x over previous
//
#include <hip/hip_runtime.h>
#include <hip/hip_bf16.h>

#define PB 8
#define PS 1024
#define PD 512
#define PH 8

typedef __attribute__((ext_vector_type(8))) short short8;
typedef __attribute__((ext_vector_type(4))) float f32x4;

__device__ inline ushort f2bf(float x) {
    union { float f; unsigned u; } c; c.f = x;
    unsigned u = c.u + 0x7fffu + ((c.u >> 16) & 1u);
    return (ushort)(u >> 16);
}
__device__ inline float bf2f(ushort u) {
    union { unsigned u; float f; } c; c.u = (unsigned)u << 16; return c.f;
}

__device__ inline void gload16(const void* g, void* l) {
    __builtin_amdgcn_global_load_lds(
        (const __attribute__((address_space(1))) void*)g,
        (__attribute__((address_space(3))) void*)l, 16, 0, 0);
}

// ---------------------------------------------------------------------------
// One dispatch for all 6 bf16 casts.
// ---------------------------------------------------------------------------
__global__ __launch_bounds__(256)
void cast_all(const float* __restrict__ q, const float* __restrict__ k,
              const float* __restrict__ v, const float* __restrict__ Wq,
              const float* __restrict__ Wv, const float* __restrict__ Wo,
              ushort* __restrict__ q_bf, ushort* __restrict__ k_bf,
              ushort* __restrict__ v_bf, ushort* __restrict__ Wq_bf,
              ushort* __restrict__ Wv_bf, ushort* __restrict__ Wo_bf)
{
    const int bid = blockIdx.x;
    const float* s; ushort* d; int base;
    if      (bid < 4096)  { s = q;  d = q_bf;  base = bid; }
    else if (bid < 8192)  { s = k;  d = k_bf;  base = bid - 4096; }
    else if (bid < 12288) { s = v;  d = v_bf;  base = bid - 8192; }
    else if (bid < 12544) { s = Wq; d = Wq_bf; base = bid - 12288; }
    else if (bid < 12800) { s = Wv; d = Wv_bf; base = bid - 12544; }
    else                  { s = Wo; d = Wo_bf; base = bid - 12800; }
    const int i = base * 256 + threadIdx.x;
    const float4 x = ((const float4*)s)[i];
    ushort4 o;
    o.x = f2bf(x.x); o.y = f2bf(x.y); o.z = f2bf(x.z); o.w = f2bf(x.w);
    ((ushort4*)d)[i] = o;
}

// ---------------------------------------------------------------------------
// All three projections in one dispatch (blockIdx.z = 0:q, 1:k, 2:v).
// z<2 -> bf16 head-split [(b*8+h)*1024+s][64]; z==2 -> plain V^T
// vhT[(b*8+h)*64+d][1024 s]. Epilogue: LDS C-bounce -> coalesced 16B stores.
// ---------------------------------------------------------------------------
__global__ __launch_bounds__(256)
void proj3(const ushort* __restrict__ q_bf, const ushort* __restrict__ k_bf,
           const ushort* __restrict__ v_bf, const ushort* __restrict__ Wq_bf,
           const ushort* __restrict__ Wv_bf, const float* __restrict__ bq,
           const float* __restrict__ bv, ushort* __restrict__ qh,
           ushort* __restrict__ kh, ushort* __restrict__ vhT)
{
    const int z = blockIdx.z;
    const ushort* A = (z == 0) ? q_bf : (z == 1) ? k_bf : v_bf;
    const ushort* B = (z == 2) ? Wv_bf : Wq_bf;
    const float* bias = (z == 2) ? bv : bq;

    __shared__ __align__(16) ushort S[128 * 136];   // 34.8 KB
    ushort* As = S;            // [0, 8192)
    ushort* Bs = S + 8192;     // [8192, 16384)
    const int tid = threadIdx.x;
    const int lane = tid & 63;
    const int wave = tid >> 6;
    const int wr = wave >> 1, wc = wave & 1;
    const int bm = blockIdx.x * 128, bn = blockIdx.y * 128;
    const int lrow = lane >> 3;
    const int lcol = (lane & 7) * 8;

    f32x4 acc[4][4] = {};

    for (int k0 = 0; k0 < 512; k0 += 64) {
#pragma unroll
        for (int i = 0; i < 4; ++i) {
            const int c = wave * 4 + i;
            gload16(A + (size_t)(bm + c * 8 + lrow) * 512 + k0 + lcol, &As[c * 512]);
            gload16(B + (size_t)(bn + c * 8 + lrow) * 512 + k0 + lcol, &Bs[c * 512]);
        }
        __syncthreads();
        short8 af[2][4], bf[2][4];
#pragma unroll
        for (int kk = 0; kk < 2; ++kk) {
#pragma unroll
            for (int m = 0; m < 4; ++m)
                af[kk][m] = *(const short8*)&As[(wr * 64 + m * 16 + (lane & 15)) * 64 + kk * 32 + (lane >> 4) * 8];
#pragma unroll
            for (int n = 0; n < 4; ++n)
                bf[kk][n] = *(const short8*)&Bs[(wc * 64 + n * 16 + (lane & 15)) * 64 + kk * 32 + (lane >> 4) * 8];
        }
#pragma unroll
        for (int kk = 0; kk < 2; ++kk)
#pragma unroll
            for (int m = 0; m < 4; ++m)
#pragma unroll
                for (int n = 0; n < 4; ++n)
                    acc[m][n] = __builtin_amdgcn_mfma_f32_16x16x32_bf16(af[kk][m], bf[kk][n], acc[m][n], 0, 0, 0);
        __syncthreads();
    }

    // ---- stage C into LDS (bf16, stride 136) ----
    if (z == 2) {
        // transposed: S[col*136 + row] so vhT streams contiguous in s
#pragma unroll
        for (int m = 0; m < 4; ++m)
#pragma unroll
            for (int n = 0; n < 4; ++n) {
                const int r0 = wr * 64 + m * 16 + (lane >> 4) * 4;
                const int cl = wc * 64 + n * 16 + (lane & 15);
                const float bi = bias[bn + cl];
                ushort4 o;
                o.x = f2bf(acc[m][n][0] + bi);
                o.y = f2bf(acc[m][n][1] + bi);
                o.z = f2bf(acc[m][n][2] + bi);
                o.w = f2bf(acc[m][n][3] + bi);
                *(ushort4*)&S[cl * 136 + r0] = o;
            }
    } else {
#pragma unroll
        for (int m = 0; m < 4; ++m)
#pragma unroll
            for (int n = 0; n < 4; ++n) {
                const int r0 = wr * 64 + m * 16 + (lane >> 4) * 4;
                const int cl = wc * 64 + n * 16 + (lane & 15);
                const float bi = bias[bn + cl];
#pragma unroll
                for (int r = 0; r < 4; ++r)
                    S[(r0 + r) * 136 + cl] = f2bf(acc[m][n][r] + bi);
            }
    }
    __syncthreads();

    // ---- coalesced 16B stores: 2048 chunks, 8 per thread ----
    const int b = bm >> 10, sbase = bm & 1023;
    if (z == 2) {
#pragma unroll
        for (int it = 0; it < 8; ++it) {
            const int c = it * 256 + tid;
            const int dloc = c >> 4, seg = c & 15;      // d-local, s-chunk
            const int h = (bn >> 6) + (dloc >> 6), d = dloc & 63;
            const uint4 v4 = *(const uint4*)&S[dloc * 136 + seg * 8];
            *(uint4*)&vhT[((size_t)((b * 8 + h) * 64 + d)) * 1024 + sbase + seg * 8] = v4;
        }
    } else {
        ushort* out = z ? kh : qh;
#pragma unroll
        for (int it = 0; it < 8; ++it) {
            const int c = it * 256 + tid;
            const int row = c >> 4, seg = c & 15;       // s-local, col-chunk
            const int h = (bn >> 6) + (seg >> 3), d8 = (seg & 7) * 8;
            const uint4 v4 = *(const uint4*)&S[row * 136 + seg * 8];
            *(uint4*)&out[(((size_t)(b * 8 + h)) * 1024 + sbase + row) * 64 + d8] = v4;
        }
    }
}

// ---------------------------------------------------------------------------
// QK^T per (b,h): raw bf16 logits (x0.125) into the first 2KB of each score
// row's 4KB slot, via LDS C-bounce -> coalesced 16B stores. Upper-triangular
// 128-blocks write f32 zeros. Flat grid, bh fastest-varying (XCD L2 share).
// LPT order: heavy bottom-triangle rows (large qb) dispatch first.
// ---------------------------------------------------------------------------
__global__ __launch_bounds__(256)
void qk_mfma(const ushort* __restrict__ qh, const ushort* __restrict__ kh,
             float* __restrict__ scores)
{
    const int d0 = blockIdx.x;           // 0..4095
    const int bh = d0 & 63;
    const int pair = d0 >> 6;            // 0..63
    const int kb = pair & 7, qb = 7 - (pair >> 3);   // heavy qb first
    const int tid = threadIdx.x;
    if (kb > qb) {
        // masked region: write final zeros
        float* S = scores + ((size_t)bh << 20);
        const f32x4 z = {};
#pragma unroll
        for (int it = 0; it < 16; ++it) {
            const int f = it * 256 + tid;           // 4096 float4 total
            const int row = f >> 5, c4 = f & 31;
            __builtin_nontemporal_store(z,
                (f32x4*)&S[(size_t)(qb * 128 + row) * 1024 + kb * 128 + c4 * 4]);
        }
        return;
    }
    __shared__ __align__(16) ushort S[128 * 136];   // 34.8 KB
    ushort* As = S;
    ushort* Bs = S + 8192;
    const int lane = tid & 63, wave = tid >> 6;
    const int wr = wave >> 1, wc = wave & 1;
    const ushort* Ab = qh + ((size_t)bh * PS + qb * 128) * 64;
    const ushort* Bb = kh + ((size_t)bh * PS + kb * 128) * 64;

#pragma unroll
    for (int i = 0; i < 4; ++i) {
        const int c = wave * 4 + i;
        gload16(Ab + c * 512 + lane * 8, &As[c * 512]);
        gload16(Bb + c * 512 + lane * 8, &Bs[c * 512]);
    }
    __syncthreads();

    f32x4 acc[4][4] = {};
    short8 af[2][4], bf[2][4];
#pragma unroll
    for (int kk = 0; kk < 2; ++kk) {
#pragma unroll
        for (int m = 0; m < 4; ++m)
            af[kk][m] = *(const short8*)&As[(wr * 64 + m * 16 + (lane & 15)) * 64 + kk * 32 + (lane >> 4) * 8];
#pragma unroll
        for (int n = 0; n < 4; ++n)
            bf[kk][n] = *(const short8*)&Bs[(wc * 64 + n * 16 + (lane & 15)) * 64 + kk * 32 + (lane >> 4) * 8];
    }
#pragma unroll
    for (int kk = 0; kk < 2; ++kk)
#pragma unroll
        for (int m = 0; m < 4; ++m)
#pragma unroll
            for (int n = 0; n < 4; ++n)
                acc[m][n] = __builtin_amdgcn_mfma_f32_16x16x32_bf16(af[kk][m], bf[kk][n], acc[m][n], 0, 0, 0);

    __syncthreads();   // all fragment reads done before C overwrites S

    // ---- stage C bf16 (x0.125) into LDS, stride 136 ----
#pragma unroll
    for (int m = 0; m < 4; ++m)
#pragma unroll
        for (int n = 0; n < 4; ++n) {
            const int r0 = wr * 64 + m * 16 + (lane >> 4) * 4;
            const int cl = wc * 64 + n * 16 + (lane & 15);
#pragma unroll
            for (int r = 0; r < 4; ++r)
                S[(r0 + r) * 136 + cl] = f2bf(acc[m][n][r] * 0.125f);
        }
    __syncthreads();

    // ---- coalesced 16B stores of the raw tile ----
    ushort* Sr = (ushort*)(scores + ((size_t)bh << 20));
#pragma unroll
    for (int it = 0; it < 8; ++it) {
        const int c = it * 256 + tid;
        const int row = c >> 4, seg = c & 15;
        const uint4 v4 = *(const uint4*)&S[row * 136 + seg * 8];
        *(uint4*)&Sr[(size_t)(qb * 128 + row) * 2048 + kb * 128 + seg * 8] = v4;
    }
}

// ---------------------------------------------------------------------------
// Fused row softmax + PV, v3: 512 threads = 8 waves = 8 rows per block.
// Final score stores are REGULAR (cached) stores (r13: NT partial-chunk
// stores showed 2.6x write amplification). Register-lean row phase (no
// cum[]; r15/r17 falsified fatter variants). LPT order: deepest row-blocks
// (largest nt) dispatch first to shave the straggler tail.
// ---------------------------------------------------------------------------
__global__ __launch_bounds__(512, 8)
void rowpv3(float* __restrict__ scores, const ushort* __restrict__ vhT,
            const float* __restrict__ gammas, ushort* __restrict__ attn)
{
    const int d0 = blockIdx.x;           // 0..8191
    const int bh = d0 & 63, h = bh & 7;
    const int b = bh >> 3;
    const int rb = 127 - (d0 >> 6);      // 8-row block, deepest first
    const int w = threadIdx.x >> 6;      // wave = row within block, 0..7
    const int lane = threadIdx.x & 63;
    const int i = rb * 8 + w;
    const int nt = (rb >> 3) + 1;        // 64-col k-tiles for this block
    const int G = (nt + 3) >> 2;         // 1..4 col-groups of 4 per lane
    const int base = lane * 4 * G;       // covers [0, 256G) >= nt*64
    const int lim = ((i >> 7) + 1) * 128;

    __shared__ __align__(16) ushort P[8 * 1024];    // 16 KB, swizzled
    __shared__ float RED[2][8][68];                 // 4.3 KB padded

    float* srow = scores + ((size_t)bh << 20) + ((size_t)i << 10);
    const ushort* rraw = (const ushort*)srow;

    union U4 { uint2 v; ushort u[4]; };
    float l[16];
#pragma unroll
    for (int g = 0; g < 4; ++g) {
        if (g < G) {
            U4 a; a.v = *(const uint2*)(rraw + base + g * 4);
#pragma unroll
            for (int j = 0; j < 4; ++j)
                l[g * 4 + j] = (base + g * 4 + j <= i) ? bf2f(a.u[j]) : -3.0e38f;
        }
    }

    // softmax-1 max
    float m1 = -3.0e38f;
#pragma unroll
    for (int g = 0; g < 4; ++g) if (g < G)
#pragma unroll
        for (int j = 0; j < 4; ++j) m1 = fmaxf(m1, l[g * 4 + j]);
#pragma unroll
    for (int off = 32; off; off >>= 1) m1 = fmaxf(m1, __shfl_xor(m1, off));

    // lane sum of exp (masked cols underflow to 0)
    float lsum = 0.f;
#pragma unroll
    for (int g = 0; g < 4; ++g) if (g < G)
#pragma unroll
        for (int j = 0; j < 4; ++j) lsum += __expf(l[g * 4 + j] - m1);
    // single 64-lane scan of lane totals
    float incl = lsum;
#pragma unroll
    for (int off = 1; off < 64; off <<= 1) {
        const float y = __shfl_up(incl, off);
        if (lane >= off) incl += y;
    }
    const float excl = incl - lsum;
    const float es = __shfl(incl, 63);
    const float inv_es = __builtin_amdgcn_rcpf(es);
    const float gamma = -fabsf(gammas[h]);
    const float M2 = fmaxf(m1, 0.f);     // shift for softmax-2 (exact)

    // decay + softmax-2 numerator (running cumsum recompute)
    float racc = excl;
    float s2 = 0.f;
#pragma unroll
    for (int g = 0; g < 4; ++g) if (g < G)
#pragma unroll
        for (int j = 0; j < 4; ++j) {
            const int c = g * 4 + j;
            if (base + c <= i) {
                racc += __expf(l[c] - m1);
                const float sfxn = fmaxf((es - racc) * inv_es, 0.f);
                const float pe = (float)(i - (base + c));
                const float dist = __builtin_amdgcn_sqrtf(sfxn * pe);
                const float eff = fmaxf(__expf(gamma * dist), 1e-5f);
                const float p = __expf(l[c] * eff - M2);
                l[c] = p; s2 += p;
            } else {
                l[c] = 0.f;
            }
        }
#pragma unroll
    for (int off = 32; off; off >>= 1) s2 += __shfl_xor(s2, off);
    const float inv2 = __builtin_amdgcn_rcpf(s2);
#pragma unroll
    for (int g = 0; g < 4; ++g) if (g < G)
#pragma unroll
        for (int j = 0; j < 4; ++j) l[g * 4 + j] *= inv2;

    // ---- P -> LDS bf16; logical 16B chunk lc -> physical (lc&~7)|((lc^w)&7)
#pragma unroll
    for (int g = 0; g < 4; ++g) {
        if (g < G) {
            U4 p;
#pragma unroll
            for (int j = 0; j < 4; ++j) p.u[j] = f2bf(l[g * 4 + j]);
            const int col = base + g * 4;
            const int lc = col >> 3;
            const int sp = (lc & ~7) | ((lc ^ w) & 7);
            *(uint2*)&P[w * 1024 + sp * 8 + (col & 7)] = p.v;
        }
    }
    __syncthreads();

    // ---- final f32 score stores: REGULAR stores (L2 write-combining)
#pragma unroll
    for (int g = 0; g < 4; ++g) {
        if (g < G && base + g * 4 < lim) {
            f32x4 v;
            v[0] = l[g * 4 + 0]; v[1] = l[g * 4 + 1];
            v[2] = l[g * 4 + 2]; v[3] = l[g * 4 + 3];
            *(f32x4*)&srow[base + g * 4] = v;
        }
    }

    // ---- PV MFMA: waves (kq in 0..1, nn in 0..3); A rows 8-15 duplicated,
    // their C rows discarded. V^T direct from global (L2).
    const int kq = w >> 2, nn = w & 3;
    const int row16 = lane & 15, kg = lane >> 4;
    const int arow = lane & 7;           // P row supplied to the A-fragment
    const ushort* vb = vhT + ((size_t)bh << 16) + (size_t)(nn * 16 + row16) * 1024;
    f32x4 acc = {};
    for (int t = kq; t < nt; t += 2) {
#pragma unroll
        for (int kk = 0; kk < 2; ++kk) {
            const int chunk = t * 8 + ((kk * 4 + kg) ^ arow);
            const short8 af = *(const short8*)&P[arow * 1024 + chunk * 8];
            const short8 bf = *(const short8*)&vb[t * 64 + kk * 32 + kg * 8];
            acc = __builtin_amdgcn_mfma_f32_16x16x32_bf16(af, bf, acc, 0, 0, 0);
        }
    }

    // ---- reduce 2 kq partials (C rows 0..7 only), write attn
    if (kg < 2) {
#pragma unroll
        for (int r = 0; r < 4; ++r)
            RED[kq][kg * 4 + r][nn * 16 + row16] = acc[r];
    }
    __syncthreads();
    const float o = RED[0][w][lane] + RED[1][w][lane];
    attn[((size_t)(b * 1024 + i)) * 512 + h * 64 + lane] = f2bf(o);
}

// ---------------------------------------------------------------------------
// Output GEMM: f32 out = attn(bf16) @ Wo^T + bo
// ---------------------------------------------------------------------------
__global__ __launch_bounds__(256)
void gemm_out(const ushort* __restrict__ A, const ushort* __restrict__ B,
              const float* __restrict__ bias, float* __restrict__ out)
{
    __shared__ __align__(16) ushort As[128 * 64];
    __shared__ __align__(16) ushort Bs[128 * 64];
    const int tid = threadIdx.x;
    const int lane = tid & 63;
    const int wave = tid >> 6;
    const int wr = wave >> 1, wc = wave & 1;
    const int bm = blockIdx.x * 128, bn = blockIdx.y * 128;
    const int lrow = lane >> 3;
    const int lcol = (lane & 7) * 8;

    f32x4 acc[4][4] = {};

    for (int k0 = 0; k0 < 512; k0 += 64) {
#pragma unroll
        for (int i = 0; i < 4; ++i) {
            const int c = wave * 4 + i;
            gload16(A + (size_t)(bm + c * 8 + lrow) * 512 + k0 + lcol, &As[c * 512]);
            gload16(B + (size_t)(bn + c * 8 + lrow) * 512 + k0 + lcol, &Bs[c * 512]);
        }
        __syncthreads();
        short8 af[2][4], bf[2][4];
#pragma unroll
        for (int kk = 0; kk < 2; ++kk) {
#pragma unroll
            for (int m = 0; m < 4; ++m)
                af[kk][m] = *(const short8*)&As[(wr * 64 + m * 16 + (lane & 15)) * 64 + kk * 32 + (lane >> 4) * 8];
#pragma unroll
            for (int n = 0; n < 4; ++n)
                bf[kk][n] = *(const short8*)&Bs[(wc * 64 + n * 16 + (lane & 15)) * 64 + kk * 32 + (lane >> 4) * 8];
        }
#pragma unroll
        for (int kk = 0; kk < 2; ++kk)
#pragma unroll
            for (int m = 0; m < 4; ++m)
#pragma unroll
                for (int n = 0; n < 4; ++n)
                    acc[m][n] = __builtin_amdgcn_mfma_f32_16x16x32_bf16(af[kk][m], bf[kk][n], acc[m][n], 0, 0, 0);
        __syncthreads();
    }

#pragma unroll
    for (int m = 0; m < 4; ++m)
#pragma unroll
        for (int n = 0; n < 4; ++n)
#pragma unroll
            for (int r = 0; r < 4; ++r) {
                const int row = bm + wr * 64 + m * 16 + (lane >> 4) * 4 + r;
                const int col = bn + wc * 64 + n * 16 + (lane & 15);
                out[(size_t)row * 512 + col] = acc[m][n][r] + bias[col];
            }
}

// ---------------------------------------------------------------------------
extern "C" void kernel_launch(void* const* d_in, const int* in_sizes, int n_in,
                              void* d_out, int out_size, void* d_ws, size_t ws_size,
                              hipStream_t stream)
{
    const float* q      = (const float*)d_in[0];
    const float* k      = (const float*)d_in[1];
    const float* v      = (const float*)d_in[2];
    const float* Wq     = (const float*)d_in[4];
    const float* bq     = (const float*)d_in[5];
    const float* Wv     = (const float*)d_in[6];
    const float* bv     = (const float*)d_in[7];
    const float* Wo     = (const float*)d_in[8];
    const float* bo     = (const float*)d_in[9];
    const float* gammas = (const float*)d_in[10];

    float* out    = (float*)d_out;                       // [8,1024,512] f32
    float* scores = out + (size_t)PB * PS * PD;          // [64,1024,1024] f32

    char* w = (char*)d_ws;
    ushort* q_bf  = (ushort*)(w);                        // 8 MB
    ushort* k_bf  = (ushort*)(w + (8u  << 20));          // 8 MB
    ushort* v_bf  = (ushort*)(w + (16u << 20));          // 8 MB
    ushort* Wq_bf = (ushort*)(w + (24u << 20));          // 0.5 MB
    ushort* Wv_bf = (ushort*)(w + (24u << 20) + (1u << 19));
    ushort* Wo_bf = (ushort*)(w + (25u << 20));
    ushort* qh    = (ushort*)(w + (26u << 20));          // 8 MB
    ushort* kh    = (ushort*)(w + (34u << 20));          // 8 MB
    ushort* vhT   = (ushort*)(w + (42u << 20));          // 8 MB (plain transpose)
    ushort* attn  = (ushort*)(w + (50u << 20));          // 8 MB

    cast_all<<<13056, 256, 0, stream>>>(q, k, v, Wq, Wv, Wo,
                                        q_bf, k_bf, v_bf, Wq_bf, Wv_bf, Wo_bf);

    proj3<<<dim3(64, 4, 3), 256, 0, stream>>>(q_bf, k_bf, v_bf, Wq_bf, Wv_bf,
                                              bq, bv, qh, kh, vhT);

    qk_mfma<<<4096, 256, 0, stream>>>(qh, kh, scores);
    rowpv3<<<8192, 512, 0, stream>>>(scores, vhT, gammas, attn);

    gemm_out<<<dim3(64, 4), 256, 0, stream>>>(attn, Wo_bf, bo, out);
}